// Round 5
// baseline (105.260 us; speedup 1.0000x reference)
//
#include <hip/hip_runtime.h>
#include <stdint.h>
#include <stddef.h>

typedef int   v4i  __attribute__((ext_vector_type(4)));
typedef int   v16i __attribute__((ext_vector_type(16)));
typedef float v4f  __attribute__((ext_vector_type(4)));

#define M_DIM 32768
#define N_DIM 1024
#define K_DIM 1024
#define BM 256
#define BN 256
#define BK 64             // int8 elems per K-tile (64 B rows in LDS)
#define NT (K_DIM / BK)   // 16 K-tiles

typedef const __attribute__((address_space(1))) void gvoid_t;
typedef __attribute__((address_space(3))) void lvoid_t;

__device__ __forceinline__ void gload16(const void* g, void* l) {
    __builtin_amdgcn_global_load_lds((gvoid_t*)g, (lvoid_t*)l, 16, 0, 0);
}

#define VMCNT0()  asm volatile("s_waitcnt vmcnt(0)" ::: "memory")
// Hardened barrier: memory clobber stops IR-level load/store motion across it
// (raw s_barrier builtin is IntrNoMem — the R3 race); sched_barrier pins MIR.
#define BARRIER() do { asm volatile("s_barrier" ::: "memory"); \
                       __builtin_amdgcn_sched_barrier(0); } while (0)

// ---------------- pass 0: repack weight int32 -> packed int8 ----------------
__global__ __launch_bounds__(256)
void repack_w_kernel(const int* __restrict__ wi, int* __restrict__ wq, int n4)
{
    int i = blockIdx.x * blockDim.x + threadIdx.x;
    if (i < n4) {
        v4i v = ((const v4i*)wi)[i];
        wq[i] = (v[0] & 255) | ((v[1] & 255) << 8) |
                ((v[2] & 255) << 16) | ((v[3] & 255) << 24);
    }
}

// ---------------- pass 1: quantize fp32 -> int8 (row-major [M][K]) ----------
__global__ __launch_bounds__(256, 2)
void quant_kernel(const float* __restrict__ x, int* __restrict__ q,
                  const float* __restrict__ iscale_p, int n4)
{
    const float inv = 1.0f / *iscale_p;
    int idx = blockIdx.x * blockDim.x + threadIdx.x;
    int stride = gridDim.x * blockDim.x;
    const v4f* xp = (const v4f*)x;
    for (int i = idx; i < n4; i += stride) {
        v4f v = xp[i];
        int r = 0;
        #pragma unroll
        for (int j = 0; j < 4; ++j) {
            float t = rintf(v[j] * inv);
            t = fminf(127.f, fmaxf(-128.f, t));
            r |= ((int)t & 255) << (8 * j);
        }
        q[i] = r;
    }
}

// ---------------- LDS swizzle (64 B rows): col ^= ((row>>1)&3)<<4 -----------
// Conflict-free for the 32x32 fragment read pattern (8 lanes per 4-bank group).
__device__ __forceinline__ int swz(int row) { return ((row >> 1) & 3) << 4; }

// Stage a [256][BK=64] int8 tile: 4 rounds, each wave DMAs 1 KiB (16 rows).
// LDS dest linear; global source inverse-swizzled (both-sides rule).
__device__ __forceinline__ void stage64(const signed char* __restrict__ g,
                                        signed char* lds, int wv, int ln)
{
    #pragma unroll
    for (int j = 0; j < 4; ++j) {
        const int rbase = j * 64 + wv * 16;          // wave-uniform
        const int row   = rbase + (ln >> 2);
        const int src   = ((ln & 3) * 16) ^ swz(row);
        gload16(g + (size_t)row * K_DIM + src, lds + rbase * BK);
    }
}

__device__ __forceinline__ v4i frag(const signed char* lds, int row, int kb)
{
    return *(const v4i*)(lds + row * BK + (kb ^ swz(row)));
}

// ---------------- pass 2: int8 GEMM, 256x256 tile, 32x32x32 MFMA ------------
// 4 waves (2x2), 128x128 per wave = 4x4 of 32x32 frags (acc 256 VGPR).
__global__ __launch_bounds__(256)
void qgemm_kernel(const signed char* __restrict__ Aq,
                  const signed char* __restrict__ W,
                  const float* __restrict__ wscale,
                  const float* __restrict__ iscale_p,
                  const float* __restrict__ bias,
                  float* __restrict__ out)
{
    __shared__ signed char lA[2][BM * BK];   // 2 x 16 KiB
    __shared__ signed char lB[2][BN * BK];   // 2 x 16 KiB (64 KiB -> 2 blk/CU)

    // XCD-bijective swizzle: 512 blocks, 64 per XCD chunk; 4 n-blocks sharing
    // an A panel run concurrently on one XCD (panel+W = 3 MiB < 4 MiB L2).
    const int bid = blockIdx.x;
    const int wg  = (bid & 7) * 64 + (bid >> 3);
    const int m_blk = wg >> 2;
    const int n_blk = wg & 3;
    const int mrow0 = m_blk * BM;
    const int ncol0 = n_blk * BN;

    const int tid = threadIdx.x;
    const int wv  = tid >> 6;
    const int ln  = tid & 63;
    const int wm  = wv >> 1;               // 2x2 wave grid, 128x128 each
    const int wn  = wv & 1;
    const int lr  = ln & 31;               // fragment row(A)/col(B)
    const int kh  = (ln >> 5) * 16;        // k-chunk byte (0|16)

    const signed char* gA = Aq + (size_t)mrow0 * K_DIM;
    const signed char* gB = W  + (size_t)ncol0 * K_DIM;

    v16i acc[4][4] = {};

    // Prologue: tile 0 into buffer 0, drain, barrier.
    stage64(gA, lA[0], wv, ln);
    stage64(gB, lB[0], wv, ln);
    VMCNT0();
    BARRIER();

    signed char *cA = lA[0], *cB = lB[0], *nA = lA[1], *nB = lB[1];

    for (int t = 0; t < NT; ++t) {
        const bool st = (t + 1 < NT);
        if (st) {                           // prefetch next tile (other buffer)
            stage64(gA + (size_t)(t + 1) * BK, nA, wv, ln);
            stage64(gB + (size_t)(t + 1) * BK, nB, wv, ln);
        }
        #pragma unroll
        for (int ks = 0; ks < 2; ++ks) {    // two K=32 steps per tile
            v4i aF[4], bF[4];
            #pragma unroll
            for (int i = 0; i < 4; ++i) {
                aF[i] = frag(cA, wm * 128 + i * 32 + lr, ks * 32 + kh);
                bF[i] = frag(cB, wn * 128 + i * 32 + lr, ks * 32 + kh);
            }
            __builtin_amdgcn_s_setprio(1);
            #pragma unroll
            for (int i = 0; i < 4; ++i)
                #pragma unroll
                for (int j = 0; j < 4; ++j)
                    acc[i][j] = __builtin_amdgcn_mfma_i32_32x32x32_i8(
                                    aF[i], bF[j], acc[i][j], 0, 0, 0);
            __builtin_amdgcn_s_setprio(0);
        }
        if (st) VMCNT0();                   // next tile landed during compute
        BARRIER();                          // everyone done reading cur buffer
        signed char* s;
        s = cA; cA = nA; nA = s;
        s = cB; cB = nB; nB = s;
    }

    // Epilogue: dequant + bias. C/D (32x32): col = ln&31,
    // row = (reg&3) + 8*(reg>>2) + 4*(ln>>5).
    const float is = *iscale_p;
    #pragma unroll
    for (int j = 0; j < 4; ++j) {
        const int col = ncol0 + wn * 128 + j * 32 + lr;
        const float sc = wscale[col] * is;
        const float bv = bias[col];
        #pragma unroll
        for (int i = 0; i < 4; ++i) {
            const int rbase = mrow0 + wm * 128 + i * 32 + 4 * (ln >> 5);
            #pragma unroll
            for (int r = 0; r < 16; ++r) {
                const int row = rbase + (r & 3) + 8 * (r >> 2);
                out[(size_t)row * N_DIM + col] = (float)acc[i][j][r] * sc + bv;
            }
        }
    }
}

extern "C" void kernel_launch(void* const* d_in, const int* in_sizes, int n_in,
                              void* d_out, int out_size, void* d_ws, size_t ws_size,
                              hipStream_t stream)
{
    const float* x       = (const float*)d_in[0];
    const int*   w32     = (const int*)d_in[1];   // int8 weight stored as int32 [N][K]
    const float* wscale  = (const float*)d_in[2];
    const float* iscale  = (const float*)d_in[3];
    const float* bias    = (const float*)d_in[4];
    float* out           = (float*)d_out;

    signed char* aq = (signed char*)d_ws;                          // 32 MiB
    signed char* wq = (signed char*)d_ws + (size_t)M_DIM * K_DIM;  // +1 MiB

    const int wn4 = (N_DIM * K_DIM) / 4;
    repack_w_kernel<<<(wn4 + 255) / 256, 256, 0, stream>>>(w32, (int*)wq, wn4);

    quant_kernel<<<8192, 256, 0, stream>>>(x, (int*)aq, iscale, (M_DIM * K_DIM) / 4);

    const int grid = (M_DIM / BM) * (N_DIM / BN);   // 512 blocks
    qgemm_kernel<<<grid, 256, 0, stream>>>(aq, wq, wscale, iscale, bias, out);
}

// Round 6
// 85.315 us; speedup vs baseline: 1.2338x; 1.2338x over previous
//
#include <hip/hip_runtime.h>
#include <stdint.h>
#include <stddef.h>

typedef int   v4i __attribute__((ext_vector_type(4)));
typedef float v4f __attribute__((ext_vector_type(4)));

#define BM 128
#define BN 128
#define BKB 128           // int8 elems (bytes) staged per K-tile
#define M_DIM 32768
#define N_DIM 1024
#define K_DIM 1024
#define NT (K_DIM / BKB)  // 8 K-tiles
#define QN4 (M_DIM * K_DIM / 4)
#define WN4 (N_DIM * K_DIM / 4)
#define QBLOCKS 8192

typedef const __attribute__((address_space(1))) void gvoid_t;
typedef __attribute__((address_space(3))) void lvoid_t;

__device__ __forceinline__ void gload16(const void* g, void* l) {
    // global->LDS DMA, 16B/lane; LDS dest = wave-uniform base + lane*16
    __builtin_amdgcn_global_load_lds((gvoid_t*)g, (lvoid_t*)l, 16, 0, 0);
}

#define VMCNT0()  asm volatile("s_waitcnt vmcnt(0)" ::: "memory")
// Hardened barrier: memory clobber stops IR-level load/store motion across it
// (raw s_barrier builtin is IntrNoMem -> the R3 race); sched_barrier pins MIR.
#define BARRIER() do { asm volatile("s_barrier" ::: "memory"); \
                       __builtin_amdgcn_sched_barrier(0); } while (0)

// ------- pass 1 (merged): quantize x fp32->int8 AND repack W int32->int8 ----
__global__ __launch_bounds__(256)
void quant_repack_kernel(const float* __restrict__ x, int* __restrict__ q,
                         const int* __restrict__ wi, int* __restrict__ wq,
                         const float* __restrict__ iscale_p)
{
    const int b = blockIdx.x;
    if (b < QBLOCKS) {
        const float inv = 1.0f / *iscale_p;
        int idx = b * 256 + threadIdx.x;
        const int stride = QBLOCKS * 256;
        const v4f* xp = (const v4f*)x;
        for (int i = idx; i < QN4; i += stride) {
            v4f v = xp[i];
            int r = 0;
            #pragma unroll
            for (int j = 0; j < 4; ++j) {
                float t = rintf(v[j] * inv);   // round-half-even like jnp.round
                t = fminf(127.f, fmaxf(-128.f, t));
                r |= ((int)t & 255) << (8 * j);
            }
            q[i] = r;
        }
    } else {
        const int i = (b - QBLOCKS) * 256 + threadIdx.x;
        if (i < WN4) {
            v4i v = ((const v4i*)wi)[i];
            wq[i] = (v[0] & 255) | ((v[1] & 255) << 8) |
                    ((v[2] & 255) << 16) | ((v[3] & 255) << 24);
        }
    }
}

// ---------------- pass 2: int8 GEMM, C = deq(Aq * W^T) ----------------------
// 128x128 tile, 4 waves (2x2 of 64x64), 16x16x64 i8 MFMA, LDS double-buffer,
// minimal 2-phase pipeline: STAGE(t+1) issued before compute(t), one
// vmcnt(0)+barrier per K-tile.
__global__ __launch_bounds__(256, 2)
void qgemm_kernel(const signed char* __restrict__ Aq,
                  const signed char* __restrict__ W,
                  const float* __restrict__ wscale,
                  const float* __restrict__ iscale_p,
                  const float* __restrict__ bias,
                  float* __restrict__ out)
{
    __shared__ signed char lA[2][BM * BKB];   // 2 x 16 KiB
    __shared__ signed char lB[2][BN * BKB];   // 2 x 16 KiB (64 KiB total)

    // XCD-aware swizzle (2048 blocks % 8 == 0): contiguous chunk per XCD.
    const int nwg = gridDim.x;
    const int bid = blockIdx.x;
    const int wg  = (bid & 7) * (nwg >> 3) + (bid >> 3);
    const int m_blk = wg >> 3;               // 8 col-blocks per row-panel
    const int n_blk = wg & 7;
    const int mrow0 = m_blk * BM;
    const int ncol0 = n_blk * BN;

    const int tid = threadIdx.x;
    const int wv  = tid >> 6;
    const int ln  = tid & 63;
    const int wm  = wv >> 1;                 // 2x2 wave grid, 64x64 out each
    const int wn  = wv & 1;
    const int lrow = ln & 15;
    const int lk16 = (ln >> 4) << 4;
    const int swz  = (lrow & 7) << 4;        // XOR swizzle key (bits 4-6)

    const signed char* gA = Aq + (size_t)mrow0 * K_DIM;
    const signed char* gB = W  + (size_t)ncol0 * K_DIM;

    v4i acc[4][4] = {};

    // Stage one K-tile (A+B, 16KB each) into buffer `buf`. LDS linear dest;
    // global source pre-swizzled: reads apply addr^((row&7)<<4) (R2-verified).
    #define STAGE(buf, kt)                                                    \
        do {                                                                  \
            _Pragma("unroll")                                                 \
            for (int c = 0; c < 4; ++c) {                                     \
                const int o   = c * 4096 + wv * 1024 + ln * 16;               \
                const int row = o >> 7;                                       \
                const int inr = (o & 127) ^ ((row & 7) << 4);                 \
                gload16(gA + (size_t)row * K_DIM + (kt) + inr,                \
                        (void*)(lA[buf] + c * 4096 + wv * 1024));             \
                gload16(gB + (size_t)row * K_DIM + (kt) + inr,                \
                        (void*)(lB[buf] + c * 4096 + wv * 1024));             \
            }                                                                 \
        } while (0)

    // Prologue: tile 0 -> buffer 0, drain, barrier.
    STAGE(0, 0);
    VMCNT0();
    BARRIER();

    for (int t = 0; t < NT; ++t) {
        const int cur = t & 1;
        const bool st = (t + 1 < NT);
        if (st) STAGE(cur ^ 1, (t + 1) * BKB);   // issue DMA; hides under MFMA

        const signed char* cA = lA[cur];
        const signed char* cB = lB[cur];
        #pragma unroll
        for (int stp = 0; stp < 2; ++stp) {      // two K=64 steps per tile
            v4i af[4], bf[4];
            #pragma unroll
            for (int i = 0; i < 4; ++i) {
                const int arow = wm * 64 + i * 16 + lrow;
                af[i] = *(const v4i*)&cA[arow * BKB + ((stp * 64 + lk16) ^ swz)];
                const int brow = wn * 64 + i * 16 + lrow;
                bf[i] = *(const v4i*)&cB[brow * BKB + ((stp * 64 + lk16) ^ swz)];
            }
            __builtin_amdgcn_s_setprio(1);
            #pragma unroll
            for (int i = 0; i < 4; ++i)
                #pragma unroll
                for (int j = 0; j < 4; ++j)
                    acc[i][j] = __builtin_amdgcn_mfma_i32_16x16x64_i8(
                                    af[i], bf[j], acc[i][j], 0, 0, 0);
            __builtin_amdgcn_s_setprio(0);
        }
        if (st) VMCNT0();                        // next tile landed during compute
        BARRIER();                               // all waves done reading cur
    }
    #undef STAGE

    // Epilogue: dequant + bias. C/D: col = lane&15, row = (lane>>4)*4 + r.
    const float is = *iscale_p;
    const int r0 = mrow0 + wm * 64 + ((ln >> 4) << 2);
    const int c0 = ncol0 + wn * 64 + lrow;
    #pragma unroll
    for (int j = 0; j < 4; ++j) {
        const int col = c0 + j * 16;
        const float sc = wscale[col] * is;
        const float bv = bias[col];
        #pragma unroll
        for (int i = 0; i < 4; ++i) {
            const int row = r0 + i * 16;
            #pragma unroll
            for (int r = 0; r < 4; ++r)
                out[(size_t)(row + r) * N_DIM + col] = (float)acc[i][j][r] * sc + bv;
        }
    }
}

extern "C" void kernel_launch(void* const* d_in, const int* in_sizes, int n_in,
                              void* d_out, int out_size, void* d_ws, size_t ws_size,
                              hipStream_t stream)
{
    const float* x       = (const float*)d_in[0];
    const int*   w32     = (const int*)d_in[1];   // int8 weight stored as int32 [N][K]
    const float* wscale  = (const float*)d_in[2];
    const float* iscale  = (const float*)d_in[3];
    const float* bias    = (const float*)d_in[4];
    float* out           = (float*)d_out;

    signed char* aq = (signed char*)d_ws;                          // 32 MiB
    signed char* wq = (signed char*)d_ws + (size_t)M_DIM * K_DIM;  // +1 MiB

    const int wblocks = (WN4 + 255) / 256;        // 1024
    quant_repack_kernel<<<QBLOCKS + wblocks, 256, 0, stream>>>(
        x, (int*)aq, w32, (int*)wq, iscale);

    const int grid = (M_DIM / BM) * (N_DIM / BN); // 2048 blocks
    qgemm_kernel<<<grid, 256, 0, stream>>>(aq, wq, wscale, iscale, bias, out);
}

// Round 7
// 77.941 us; speedup vs baseline: 1.3505x; 1.0946x over previous
//
#include <hip/hip_runtime.h>
#include <stdint.h>
#include <stddef.h>

typedef int   v4i __attribute__((ext_vector_type(4)));
typedef float v4f __attribute__((ext_vector_type(4)));

#define M_DIM 32768
#define N_DIM 1024
#define K_DIM 1024
#define BM 64            // rows per block; block owns [64][1024] of out
#define NTILES 8         // n-tiles of 128 cols
#define KSTEPS 16        // K=1024 / 64

// ---------------- pass 0: repack W int32 [N][K] -> fragment-linear int8 -----
// W'[f][ln][16B], f = (nt*16+ks)*8 + wn*2 + jj : the exact 1KB a wave loads
// as its B-frag pair at (n-tile nt, k-step ks). Lane ln holds
// W[n = nt*128+wn*32+jj*16+(ln&15)][k = ks*64+(ln>>4)*16 .. +16].
__global__ __launch_bounds__(256)
void repack_w_kernel(const int* __restrict__ w32, int* __restrict__ wf)
{
    const int i  = blockIdx.x * 256 + threadIdx.x;   // dword index, < 262144
    const int f  = i >> 8;            // fragment id 0..1023
    const int r  = i & 255;
    const int ln = r >> 2;            // lane 0..63
    const int dw = r & 3;             // which dword of the 16B
    const int jj = f & 1;
    const int wn = (f >> 1) & 3;
    const int ks = (f >> 3) & 15;
    const int nt = f >> 7;
    const int n  = nt * 128 + wn * 32 + jj * 16 + (ln & 15);
    const int k  = ks * 64 + (ln >> 4) * 16 + dw * 4;
    const v4i v  = *(const v4i*)&w32[(size_t)n * K_DIM + k];
    wf[i] = (v[0] & 255) | ((v[1] & 255) << 8) |
            ((v[2] & 255) << 16) | ((v[3] & 255) << 24);
}

// ---------------- fused: quantize x -> LDS, then int8 GEMM + dequant --------
// 512 threads = 8 waves (2 wm x 4 wn). Per n-tile: wave computes [32][32]
// via 2x2 of 16x16x64 i8 MFMA, acc = 16 VGPR. ONE barrier in the kernel.
__global__ __launch_bounds__(512, 4)
void fused_kernel(const float* __restrict__ x,
                  const signed char* __restrict__ Wf,
                  const float* __restrict__ wscale,
                  const float* __restrict__ iscale_p,
                  const float* __restrict__ bias,
                  float* __restrict__ out)
{
    __shared__ signed char lA[BM * K_DIM];   // 64 KiB, swizzled col^((row&7)<<4)

    const int mrow0 = blockIdx.x * BM;
    const int t  = threadIdx.x;
    const int wv = t >> 6;
    const int ln = t & 63;
    const int wm = wv >> 2;              // 0..1 : m-half (32 rows)
    const int wn = wv & 3;               // 0..3 : n-quarter of the n-tile

    // ---- phase 1: load fp32 slab, quantize, swizzled LDS write ----
    {
        const float inv = 1.0f / *iscale_p;
        const int colf = (t & 255) * 4;          // int8/float column
        const int rsub = t >> 8;                 // 0..1
        for (int j = 0; j < 32; ++j) {
            const int row = j * 2 + rsub;
            const v4f v = *(const v4f*)&x[(size_t)(mrow0 + row) * K_DIM + colf];
            int r = 0;
            #pragma unroll
            for (int e = 0; e < 4; ++e) {
                float q = rintf(v[e] * inv);     // round-half-even like jnp
                q = fminf(127.f, fmaxf(-128.f, q));
                r |= ((int)q & 255) << (8 * e);
            }
            *(int*)&lA[row * K_DIM + (colf ^ ((row & 7) << 4))] = r;
        }
    }
    __syncthreads();   // the only barrier: LDS A-tile complete

    const int lr = ln & 15;
    const int kh = (ln >> 4) * 16;
    const float is = *iscale_p;

    for (int nt = 0; nt < NTILES; ++nt) {
        v4i acc[2][2] = {};
        #pragma unroll 4
        for (int ks = 0; ks < KSTEPS; ++ks) {
            v4i aF[2], bF[2];
            #pragma unroll
            for (int i = 0; i < 2; ++i) {
                const int row = wm * 32 + i * 16 + lr;
                aF[i] = *(const v4i*)&lA[row * K_DIM +
                                         ((ks * 64 + kh) ^ ((row & 7) << 4))];
            }
            #pragma unroll
            for (int j = 0; j < 2; ++j) {
                const int f = (nt * 16 + ks) * 8 + wn * 2 + j;
                bF[j] = *(const v4i*)&Wf[(size_t)f * 1024 + ln * 16];
            }
            #pragma unroll
            for (int i = 0; i < 2; ++i)
                #pragma unroll
                for (int j = 0; j < 2; ++j)
                    acc[i][j] = __builtin_amdgcn_mfma_i32_16x16x64_i8(
                                    aF[i], bF[j], acc[i][j], 0, 0, 0);
        }
        // epilogue for this n-tile: C/D col = ln&15, row = (ln>>4)*4 + r
        #pragma unroll
        for (int j = 0; j < 2; ++j) {
            const int col = nt * 128 + wn * 32 + j * 16 + lr;
            const float sc = wscale[col] * is;
            const float bv = bias[col];
            #pragma unroll
            for (int i = 0; i < 2; ++i) {
                const int rowb = mrow0 + wm * 32 + i * 16 + ((ln >> 4) << 2);
                #pragma unroll
                for (int r = 0; r < 4; ++r)
                    out[(size_t)(rowb + r) * N_DIM + col] =
                        (float)acc[i][j][r] * sc + bv;
            }
        }
    }
}

extern "C" void kernel_launch(void* const* d_in, const int* in_sizes, int n_in,
                              void* d_out, int out_size, void* d_ws, size_t ws_size,
                              hipStream_t stream)
{
    const float* x       = (const float*)d_in[0];
    const int*   w32     = (const int*)d_in[1];   // int8 weight stored as int32 [N][K]
    const float* wscale  = (const float*)d_in[2];
    const float* iscale  = (const float*)d_in[3];
    const float* bias    = (const float*)d_in[4];
    float* out           = (float*)d_out;

    signed char* wf = (signed char*)d_ws;         // 1 MiB fragment-linear W

    repack_w_kernel<<<(N_DIM * K_DIM / 4) / 256, 256, 0, stream>>>(w32, (int*)wf);

    fused_kernel<<<M_DIM / BM, 512, 0, stream>>>(x, wf, wscale, iscale, bias, out);
}

// Round 8
// 69.591 us; speedup vs baseline: 1.5126x; 1.1200x over previous
//
#include <hip/hip_runtime.h>
#include <stdint.h>
#include <stddef.h>

typedef int   v4i __attribute__((ext_vector_type(4)));
typedef float v4f __attribute__((ext_vector_type(4)));

#define M_DIM 32768
#define N_DIM 1024
#define K_DIM 1024
#define BM 64            // rows per block; block owns [64][1024] of out
#define KSTEPS 16        // K=1024 / 64

// ---------------- pass 0: repack W int32 [N][K] -> fragment-linear int8 -----
// Frag id f = ((np*8 + wv)*16 + ks)*4 + j ; np=n-pass(512 cols), wv=wave,
// j = 16-col subfrag. Lane ln dword dw holds
// W[n = np*512 + wv*64 + j*16 + (ln&15)][k = ks*64 + (ln>>4)*16 + dw*4 ..+4].
// Wave (wv) at (np,ks) streams a contiguous 4 KB: perfectly coalesced.
__global__ __launch_bounds__(256)
void repack_w_kernel(const int* __restrict__ w32, int* __restrict__ wf)
{
    const int i  = blockIdx.x * 256 + threadIdx.x;   // dword index, < 262144
    const int f  = i >> 8;            // fragment id 0..1023
    const int r  = i & 255;
    const int ln = r >> 2;            // lane 0..63
    const int dw = r & 3;             // dword within 16B
    const int j  = f & 3;
    const int ks = (f >> 2) & 15;
    const int wv = (f >> 6) & 7;
    const int np = f >> 9;
    const int n  = np * 512 + wv * 64 + j * 16 + (ln & 15);
    const int k  = ks * 64 + (ln >> 4) * 16 + dw * 4;
    const v4i v  = *(const v4i*)&w32[(size_t)n * K_DIM + k];
    wf[i] = (v[0] & 255) | ((v[1] & 255) << 8) |
            ((v[2] & 255) << 16) | ((v[3] & 255) << 24);
}

// ---------------- fused: quantize x -> LDS, then int8 GEMM + dequant --------
// 512 threads = 8 waves. Each wave owns [64 rows][64 cols] per n-pass:
// 4x4 of 16x16x64 i8 MFMA (acc 64 VGPR), 2 passes cover N=1024.
// Per k-step: 4 LDS A-frags + 4 global B-frags feed 16 MFMA.
__global__ __launch_bounds__(512, 4)
void fused_kernel(const float* __restrict__ x,
                  const signed char* __restrict__ Wf,
                  const float* __restrict__ wscale,
                  const float* __restrict__ iscale_p,
                  const float* __restrict__ bias,
                  float* __restrict__ out)
{
    __shared__ signed char lA[BM * K_DIM];   // 64 KiB, swizzled col^((row&7)<<4)

    const int mrow0 = blockIdx.x * BM;
    const int t  = threadIdx.x;
    const int wv = t >> 6;
    const int ln = t & 63;

    // ---- phase 1: load fp32 slab, quantize, swizzled LDS write ----
    {
        const float inv = 1.0f / *iscale_p;
        const int colf = (t & 255) * 4;          // int8/float column
        const int rsub = t >> 8;                 // 0..1
        for (int j = 0; j < 32; ++j) {
            const int row = j * 2 + rsub;
            const v4f v = *(const v4f*)&x[(size_t)(mrow0 + row) * K_DIM + colf];
            int r = 0;
            #pragma unroll
            for (int e = 0; e < 4; ++e) {
                float q = rintf(v[e] * inv);     // round-half-even like jnp
                q = fminf(127.f, fmaxf(-128.f, q));
                r |= ((int)q & 255) << (8 * e);
            }
            *(int*)&lA[row * K_DIM + (colf ^ ((row & 7) << 4))] = r;
        }
    }
    __syncthreads();   // the only barrier: LDS A-tile complete

    const int lr = ln & 15;
    const int kh = (ln >> 4) * 16;
    const float is = *iscale_p;

    for (int np = 0; np < 2; ++np) {
        v4i acc[4][4] = {};
        #pragma unroll 4
        for (int ks = 0; ks < KSTEPS; ++ks) {
            v4i aF[4], bF[4];
            #pragma unroll
            for (int i = 0; i < 4; ++i) {
                const int row = i * 16 + lr;
                aF[i] = *(const v4i*)&lA[row * K_DIM +
                                         ((ks * 64 + kh) ^ ((row & 7) << 4))];
            }
            const size_t fbase = ((size_t)(np * 8 + wv) * 16 + ks) * 4;
            #pragma unroll
            for (int j = 0; j < 4; ++j)
                bF[j] = *(const v4i*)&Wf[(fbase + j) * 1024 + ln * 16];
            #pragma unroll
            for (int i = 0; i < 4; ++i)
                #pragma unroll
                for (int j = 0; j < 4; ++j)
                    acc[i][j] = __builtin_amdgcn_mfma_i32_16x16x64_i8(
                                    aF[i], bF[j], acc[i][j], 0, 0, 0);
        }
        // epilogue for this n-pass: C/D col = ln&15, row = (ln>>4)*4 + r
        const int c00 = np * 512 + wv * 64;
        #pragma unroll
        for (int j = 0; j < 4; ++j) {
            const int col = c00 + j * 16 + lr;
            const float sc = wscale[col] * is;
            const float bv = bias[col];
            #pragma unroll
            for (int i = 0; i < 4; ++i) {
                const int rowb = mrow0 + i * 16 + ((ln >> 4) << 2);
                #pragma unroll
                for (int r = 0; r < 4; ++r)
                    out[(size_t)(rowb + r) * N_DIM + col] =
                        (float)acc[i][j][r] * sc + bv;
            }
        }
    }
}

extern "C" void kernel_launch(void* const* d_in, const int* in_sizes, int n_in,
                              void* d_out, int out_size, void* d_ws, size_t ws_size,
                              hipStream_t stream)
{
    const float* x       = (const float*)d_in[0];
    const int*   w32     = (const int*)d_in[1];   // int8 weight stored as int32 [N][K]
    const float* wscale  = (const float*)d_in[2];
    const float* iscale  = (const float*)d_in[3];
    const float* bias    = (const float*)d_in[4];
    float* out           = (float*)d_out;

    signed char* wf = (signed char*)d_ws;         // 1 MiB fragment-linear W

    repack_w_kernel<<<(N_DIM * K_DIM / 4) / 256, 256, 0, stream>>>(w32, (int*)wf);

    fused_kernel<<<M_DIM / BM, 512, 0, stream>>>(x, wf, wscale, iscale, bias, out);
}